// Round 5
// baseline (206.497 us; speedup 1.0000x reference)
//
#include <hip/hip_runtime.h>
#include <hip/hip_bf16.h>

#define NBATCH 2
#define SEQ    2048
#define DMODEL 1024
#define NHEAD  16
#define DHEAD  64
#define NHTOT  (NBATCH*NHEAD)   // 32

typedef __attribute__((ext_vector_type(8)))  short          short8;
typedef __attribute__((ext_vector_type(4)))  float          f32x4;
typedef __attribute__((ext_vector_type(16))) float          f32x16;
typedef __attribute__((ext_vector_type(4)))  unsigned short ushort4v;

__device__ __forceinline__ unsigned short f2bf(float x) {
  union { __hip_bfloat16 b; unsigned short u; } c;
  c.b = __float2bfloat16(x);
  return c.u;
}

__device__ __forceinline__ unsigned int cvt_pk_bf16(float lo, float hi) {
  unsigned int r;
  asm("v_cvt_pk_bf16_f32 %0, %1, %2" : "=v"(r) : "v"(lo), "v"(hi));
  return r;
}

// async global->LDS, 16B per lane; LDS dest = wave-uniform base + lane*16
__device__ __forceinline__ void gl_lds16(const unsigned short* g, unsigned short* l) {
  __builtin_amdgcn_global_load_lds(
      (const __attribute__((address_space(1))) void*)g,
      (__attribute__((address_space(3))) void*)l, 16, 0, 0);
}

// ---------------------------------------------------------------------------
// Kernel 1: Q,K fp32 -> bf16, per-head layout [NH][L][DK]; Q pre-scaled by
// log2(e)/sqrt(DK) so softmax = exp2(s - max). 8 elems/thread, 16B stores.
// ---------------------------------------------------------------------------
__global__ __launch_bounds__(256) void cvt_qk(const float* __restrict__ q,
                                              const float* __restrict__ k,
                                              unsigned short* __restrict__ qb,
                                              unsigned short* __restrict__ kb) {
  const float QSCALE = 0.125f * 1.44269504088896340736f;  // log2(e)/sqrt(64)
  int e = (blockIdx.x * 256 + threadIdx.x) * 8;
  int n = e >> 21;
  int r = e & ((1 << 21) - 1);
  int l = r >> 10;
  int c = r & 1023;
  int h = c >> 6;
  int d = c & 63;              // multiple of 8, stays within one head
  size_t dst = ((size_t)(n * NHEAD + h) * SEQ + l) * DHEAD + d;
  float4 q0 = *reinterpret_cast<const float4*>(q + e);
  float4 q1 = *reinterpret_cast<const float4*>(q + e + 4);
  float4 k0 = *reinterpret_cast<const float4*>(k + e);
  float4 k1 = *reinterpret_cast<const float4*>(k + e + 4);
  union { unsigned short u[8]; short8 s; } qo, ko;
  qo.u[0]=f2bf(q0.x*QSCALE); qo.u[1]=f2bf(q0.y*QSCALE);
  qo.u[2]=f2bf(q0.z*QSCALE); qo.u[3]=f2bf(q0.w*QSCALE);
  qo.u[4]=f2bf(q1.x*QSCALE); qo.u[5]=f2bf(q1.y*QSCALE);
  qo.u[6]=f2bf(q1.z*QSCALE); qo.u[7]=f2bf(q1.w*QSCALE);
  ko.u[0]=f2bf(k0.x); ko.u[1]=f2bf(k0.y); ko.u[2]=f2bf(k0.z); ko.u[3]=f2bf(k0.w);
  ko.u[4]=f2bf(k1.x); ko.u[5]=f2bf(k1.y); ko.u[6]=f2bf(k1.z); ko.u[7]=f2bf(k1.w);
  *reinterpret_cast<short8*>(qb + dst) = qo.s;
  *reinterpret_cast<short8*>(kb + dst) = ko.s;
}

// ---------------------------------------------------------------------------
// Kernel 2: V fp32 -> bf16 transposed per head: Vt[NH][DK][L]
// float4 loads, 8B transposed stores via LDS.
// ---------------------------------------------------------------------------
__global__ __launch_bounds__(256) void vtrans(const float* __restrict__ v,
                                              unsigned short* __restrict__ vt) {
  __shared__ __align__(16) unsigned short t[64][76];
  int bid = blockIdx.x;
  int nh = bid >> 5;
  int lt = bid & 31;
  int n = nh >> 4, h = nh & 15;
  int lbase = lt * 64;
  #pragma unroll
  for (int p = 0; p < 4; ++p) {
    int idx = p * 256 + threadIdx.x;
    int e = idx * 4;
    int l = e >> 6, d = e & 63;  // d multiple of 4
    float4 x = *reinterpret_cast<const float4*>(
        v + ((size_t)n * SEQ + lbase + l) * DMODEL + h * DHEAD + d);
    ushort4v o;
    o.x = f2bf(x.x); o.y = f2bf(x.y); o.z = f2bf(x.z); o.w = f2bf(x.w);
    *reinterpret_cast<ushort4v*>(&t[l][d]) = o;
  }
  __syncthreads();
  #pragma unroll
  for (int p = 0; p < 4; ++p) {
    int idx = p * 256 + threadIdx.x;
    int d = idx >> 4, lq = (idx & 15) * 4;
    ushort4v o;
    o.x = t[lq + 0][d]; o.y = t[lq + 1][d];
    o.z = t[lq + 2][d]; o.w = t[lq + 3][d];
    *reinterpret_cast<ushort4v*>(
        vt + ((size_t)nh * DHEAD + d) * SEQ + lbase + lq) = o;
  }
}

// ---------------------------------------------------------------------------
// Kernel 3: fc weight fp32 -> bf16, 8 elems/thread
// ---------------------------------------------------------------------------
__global__ __launch_bounds__(256) void cvt_w(const float* __restrict__ w,
                                             unsigned short* __restrict__ wb) {
  int e = (blockIdx.x * 256 + threadIdx.x) * 8;
  float4 w0 = *reinterpret_cast<const float4*>(w + e);
  float4 w1 = *reinterpret_cast<const float4*>(w + e + 4);
  union { unsigned short u[8]; short8 s; } wo;
  wo.u[0]=f2bf(w0.x); wo.u[1]=f2bf(w0.y); wo.u[2]=f2bf(w0.z); wo.u[3]=f2bf(w0.w);
  wo.u[4]=f2bf(w1.x); wo.u[5]=f2bf(w1.y); wo.u[6]=f2bf(w1.z); wo.u[7]=f2bf(w1.w);
  *reinterpret_cast<short8*>(wb + e) = wo.s;
}

// ---------------------------------------------------------------------------
// Kernel 4: flash attention. 4 waves x QBLK=32 = 128 q/block, grid 512
// (2+ blocks/CU). mfma_32x32x16, swapped both ways (S[key][q], O[d][q]) so
// softmax state is lane-local. T14 async reg-staging: global loads issued at
// iter start (latency hidden under QK+softmax), ds_write_b128 to swizzled
// LDS dest after; ONE barrier per iter, no vmem drain at barrier.
// T12 cvt_pk+permlane P-pack, T13 defer-max, T5 setprio around MFMA.
// LDS pointers computed inline (no initialized pointer arrays: addrspacecast
// in a static initializer fails to compile on gfx950).
// ---------------------------------------------------------------------------
__global__ __launch_bounds__(256, 2) void attn_fwd(const unsigned short* __restrict__ Qb,
                                                   const unsigned short* __restrict__ Kb,
                                                   const unsigned short* __restrict__ Vt,
                                                   unsigned short* __restrict__ Ab) {
  __shared__ __align__(16) unsigned short smem[4 * 4096];  // 32KB: K dbuf | V dbuf

  const int bid = blockIdx.x;
  // XCD swizzle (T1): XCD = bid&7 owns 4 heads (K/V 2MB, L2-resident)
  const int nh = (bid & 7) * 4 + (bid >> 7);
  const int qt = (bid >> 3) & 15;
  const int tid  = threadIdx.x;
  const int wave = tid >> 6;
  const int lane = tid & 63;
  const int l31  = lane & 31;
  const int hi   = lane >> 5;

  const unsigned short* Kb_nh = Kb + (size_t)nh * SEQ * DHEAD;
  const unsigned short* Vt_nh = Vt + (size_t)nh * DHEAD * SEQ;

  const int qglob = qt * 128 + wave * 32 + l31;

  // Q B-frag: bq[ds] = Q[q=l31][d = ds*16 + hi*8 + j]
  short8 bq[4];
  {
    const unsigned short* Qrow = Qb + ((size_t)nh * SEQ + qglob) * DHEAD + hi * 8;
    #pragma unroll
    for (int ds = 0; ds < 4; ++ds)
      bq[ds] = *reinterpret_cast<const short8*>(Qrow + ds * 16);
  }

  float m_run = -1e30f, l_run = 0.f;
  f32x16 acc[2];
  #pragma unroll
  for (int dt = 0; dt < 2; ++dt)
    #pragma unroll
    for (int r = 0; r < 16; ++r) acc[dt][r] = 0.f;

  // T14 reg staging: 2 K-chunks + 2 V-chunks of 16B per thread per tile
  int4 kreg[2], vreg[2];
  auto stage_load = [&](int kk) {
    #pragma unroll
    for (int j = 0; j < 2; ++j) {
      int c = j * 256 + tid;          // 512 chunks of 16B per 8KB tile
      int row = c >> 3, cs = c & 7;   // linear global reads
      kreg[j] = *reinterpret_cast<const int4*>(Kb_nh + (size_t)(kk + row) * DHEAD + cs * 8);
      vreg[j] = *reinterpret_cast<const int4*>(Vt_nh + (size_t)row * SEQ + kk + cs * 8);
    }
  };
  auto stage_write = [&](int buf) {
    unsigned short* kd = smem + buf * 4096;
    unsigned short* vd = smem + 2 * 4096 + buf * 4096;
    #pragma unroll
    for (int j = 0; j < 2; ++j) {
      int c = j * 256 + tid;
      int row = c >> 3, cs = c & 7;
      int dc = cs ^ (row & 7);        // swizzled LDS dest (conflict-free frag reads)
      *reinterpret_cast<int4*>(kd + (row * 8 + dc) * 8) = kreg[j];
      *reinterpret_cast<int4*>(vd + (row * 8 + dc) * 8) = vreg[j];
    }
  };

  stage_load(0);
  stage_write(0);
  __syncthreads();

  const int NT = SEQ / 64;
  for (int it = 0; it < NT; ++it) {
    const int cur = it & 1;
    const bool pf = (it + 1 < NT);
    if (pf) stage_load((it + 1) * 64);   // issue early; compute hides latency

    const unsigned short* kb = smem + cur * 4096;
    const unsigned short* vb = smem + 2 * 4096 + cur * 4096;

    // ---- QK^T: s[kt] covers keys kt*32 + (r&3)+8*(r>>2)+4*hi, q = l31 ----
    f32x16 s[2];
    __builtin_amdgcn_s_setprio(1);
    #pragma unroll
    for (int kt = 0; kt < 2; ++kt) {
      #pragma unroll
      for (int r = 0; r < 16; ++r) s[kt][r] = 0.f;
      const int row = kt * 32 + l31;
      const int sw  = row & 7;
      const unsigned short* kr = kb + row * 64;
      #pragma unroll
      for (int ds = 0; ds < 4; ++ds) {
        short8 ak = *reinterpret_cast<const short8*>(kr + (((ds * 2 + hi) ^ sw) * 8));
        s[kt] = __builtin_amdgcn_mfma_f32_32x32x16_bf16(ak, bq[ds], s[kt], 0, 0, 0);
      }
    }
    __builtin_amdgcn_s_setprio(0);

    // ---- online softmax, all lane-local (q = l31) ----
    float pmax = s[0][0];
    #pragma unroll
    for (int kt = 0; kt < 2; ++kt)
      #pragma unroll
      for (int r = 0; r < 16; ++r) pmax = fmaxf(pmax, s[kt][r]);
    pmax = fmaxf(pmax, __shfl_xor(pmax, 32));

    if (!__all(pmax - m_run <= 8.0f)) {          // T13 defer-max
      float mnew = fmaxf(m_run, pmax);
      float corr = exp2f(m_run - mnew);
      l_run *= corr;
      #pragma unroll
      for (int dt = 0; dt < 2; ++dt)
        #pragma unroll
        for (int r = 0; r < 16; ++r) acc[dt][r] *= corr;
      m_run = mnew;
    }

    float sum = 0.f;
    #pragma unroll
    for (int kt = 0; kt < 2; ++kt)
      #pragma unroll
      for (int r = 0; r < 16; ++r) {
        float p = exp2f(s[kt][r] - m_run);
        s[kt][r] = p;
        sum += p;
      }
    sum += __shfl_xor(sum, 32);
    l_run += sum;

    // ---- P -> bf16 in-register (T12): 16 cvt_pk + 8 permlane32_swap ----
    unsigned int pk[2][8];
    #pragma unroll
    for (int kt = 0; kt < 2; ++kt)
      #pragma unroll
      for (int i = 0; i < 8; ++i)
        pk[kt][i] = cvt_pk_bf16(s[kt][2 * i], s[kt][2 * i + 1]);

    unsigned int pa[4][4];
    #pragma unroll
    for (int ks = 0; ks < 4; ++ks) {
      const int t = ks >> 1, b = (ks & 1) * 4;
      pa[ks][0] = pk[t][b + 0]; pa[ks][2] = pk[t][b + 2];
      asm("v_permlane32_swap_b32 %0, %1" : "+v"(pa[ks][0]), "+v"(pa[ks][2]));
      pa[ks][1] = pk[t][b + 1]; pa[ks][3] = pk[t][b + 3];
      asm("v_permlane32_swap_b32 %0, %1" : "+v"(pa[ks][1]), "+v"(pa[ks][3]));
    }

    // ---- T14 write-late: next tile regs -> LDS[cur^1] (waits vmcnt here) ----
    if (pf) stage_write(cur ^ 1);

    // ---- PV: acc[dt] += mfma(A=Vt rows d, B=P) -> O[d][q] ----
    __builtin_amdgcn_s_setprio(1);
    #pragma unroll
    for (int dt = 0; dt < 2; ++dt) {
      const int row = dt * 32 + l31;
      const int sw  = row & 7;
      const unsigned short* vr = vb + row * 64;
      #pragma unroll
      for (int ks = 0; ks < 4; ++ks) {
        short8 av = *reinterpret_cast<const short8*>(vr + (((ks * 2 + hi) ^ sw) * 8));
        union { unsigned int u[4]; short8 s8; } pu;
        pu.u[0] = pa[ks][0]; pu.u[1] = pa[ks][1];
        pu.u[2] = pa[ks][2]; pu.u[3] = pa[ks][3];
        acc[dt] = __builtin_amdgcn_mfma_f32_32x32x16_bf16(av, pu.s8, acc[dt], 0, 0, 0);
      }
    }
    __builtin_amdgcn_s_setprio(0);
    __syncthreads();   // single barrier/iter: LDS writes visible, buffers swap
  }

  // ---- epilogue: O[d][q]/l -> transpose via LDS (reuse smem) -> bf16 rows ---
  unsigned short (*obuf)[32][76] = (unsigned short(*)[32][76])(&smem[0]);  // 19KB
  const float inv = 1.0f / l_run;     // lane-local (q = l31)
  const int n = nh >> 4, h = nh & 15;
  #pragma unroll
  for (int dt = 0; dt < 2; ++dt)
    #pragma unroll
    for (int q4 = 0; q4 < 4; ++q4) {
      ushort4v pv;
      pv.x = f2bf(acc[dt][q4 * 4 + 0] * inv);
      pv.y = f2bf(acc[dt][q4 * 4 + 1] * inv);
      pv.z = f2bf(acc[dt][q4 * 4 + 2] * inv);
      pv.w = f2bf(acc[dt][q4 * 4 + 3] * inv);
      *reinterpret_cast<ushort4v*>(&obuf[wave][l31][dt * 32 + q4 * 8 + hi * 4]) = pv;
    }
  __syncthreads();
  #pragma unroll
  for (int rep = 0; rep < 4; ++rep) {
    int idx = rep * 256 + tid;          // 128 rows x 8 chunks
    int qi = idx >> 3, ch = idx & 7;
    int w = qi >> 5, qr = qi & 31;
    union { unsigned short u[8]; short8 s; } vv;
    #pragma unroll
    for (int i = 0; i < 8; ++i) vv.u[i] = obuf[w][qr][ch * 8 + i];
    size_t orow = (size_t)n * SEQ + qt * 128 + qi;
    *reinterpret_cast<short8*>(Ab + orow * DMODEL + h * 64 + ch * 8) = vv.s;
  }
}

// ---------------------------------------------------------------------------
// Kernel 5: out = Ab(bf16) @ Wb^T + bias. 64x64 tile, BK=64, grid 1024
// (4-5 blocks/CU). gl_lds staging with inverse-swizzled global source;
// chunk-XOR swizzle -> 2-way-max bank aliasing on frag reads.
// ---------------------------------------------------------------------------
__global__ __launch_bounds__(256, 4) void fc_gemm(const unsigned short* __restrict__ Ab,
                                                  const unsigned short* __restrict__ Wb,
                                                  const float* __restrict__ bias,
                                                  float* __restrict__ out) {
  __shared__ __align__(16) unsigned short At[2][64 * 64];
  __shared__ __align__(16) unsigned short Bt[2][64 * 64];
  const int bid = blockIdx.x;
  const int bn = (bid & 7) * 2 + ((bid >> 3) & 1);  // XCD owns a Wb panel
  const int bm = bid >> 4;
  const int tid = threadIdx.x;
  const int wave = tid >> 6, lane = tid & 63;
  const int wr = wave >> 1, wc = wave & 1;
  const int l15 = lane & 15, l4 = lane >> 4;

  f32x4 acc[2][2];
  #pragma unroll
  for (int i = 0; i < 2; ++i)
    #pragma unroll
    for (int j = 0; j < 2; ++j) acc[i][j] = (f32x4){0.f, 0.f, 0.f, 0.f};

  auto stage = [&](int buf, int k0) {
    #pragma unroll
    for (int j = 0; j < 2; ++j) {
      int c = j * 256 + tid;          // 512 chunks per 8KB tile
      int row = c >> 3, cs = c & 7;
      int cg = cs ^ (row & 7);        // inverse-swizzled global chunk
      int cb = j * 256 + (tid & 192); // wave-uniform LDS chunk base
      gl_lds16(Ab + (size_t)(bm * 64 + row) * DMODEL + k0 + cg * 8, &At[buf][cb * 8]);
      gl_lds16(Wb + (size_t)(bn * 64 + row) * DMODEL + k0 + cg * 8, &Bt[buf][cb * 8]);
    }
  };

  stage(0, 0);
  __syncthreads();

  const int NT = DMODEL / 64;
  for (int it = 0; it < NT; ++it) {
    int cur = it & 1;
    if (it + 1 < NT) stage(cur ^ 1, (it + 1) * 64);

    #pragma unroll
    for (int s = 0; s < 2; ++s) {
      short8 af[2], bf2[2];
      #pragma unroll
      for (int mt = 0; mt < 2; ++mt) {
        int row = wr * 32 + mt * 16 + l15;
        af[mt] = *reinterpret_cast<const short8*>(
            &At[cur][row * 64 + (((s * 4 + l4) ^ (row & 7)) * 8)]);
      }
      #pragma unroll
      for (int nt = 0; nt < 2; ++nt) {
        int row = wc * 32 + nt * 16 + l15;
        bf2[nt] = *reinterpret_cast<const short8*>(
            &Bt[cur][row * 64 + (((s * 4 + l4) ^ (row & 7)) * 8)]);
      }
      #pragma unroll
      for (int mt = 0; mt < 2; ++mt)
        #pragma unroll
        for (int nt = 0; nt < 2; ++nt)
          acc[mt][nt] = __builtin_amdgcn_mfma_f32_16x16x32_bf16(af[mt], bf2[nt], acc[mt][nt], 0, 0, 0);
    }
    __syncthreads();
  }

  #pragma unroll
  for (int mt = 0; mt < 2; ++mt)
    #pragma unroll
    for (int nt = 0; nt < 2; ++nt) {
      int col = bn * 64 + wc * 32 + nt * 16 + l15;
      float bv = bias[col];
      #pragma unroll
      for (int r = 0; r < 4; ++r) {
        int row = bm * 64 + wr * 32 + mt * 16 + l4 * 4 + r;
        out[(size_t)row * DMODEL + col] = acc[mt][nt][r] + bv;
      }
    }
}

// ---------------------------------------------------------------------------
extern "C" void kernel_launch(void* const* d_in, const int* in_sizes, int n_in,
                              void* d_out, int out_size, void* d_ws, size_t ws_size,
                              hipStream_t stream) {
  const float* values  = (const float*)d_in[0];
  const float* keys    = (const float*)d_in[1];
  const float* queries = (const float*)d_in[2];
  const float* fc_w    = (const float*)d_in[3];
  const float* fc_b    = (const float*)d_in[4];
  float* out = (float*)d_out;

  char* ws = (char*)d_ws;
  const size_t QKV_BYTES = (size_t)NHTOT * SEQ * DHEAD * 2;  // 8 MB each
  unsigned short* Qb = (unsigned short*)(ws);
  unsigned short* Kb = (unsigned short*)(ws + QKV_BYTES);
  unsigned short* Vt = (unsigned short*)(ws + 2 * QKV_BYTES);
  unsigned short* Wb = (unsigned short*)(ws + 3 * QKV_BYTES);
  unsigned short* Ab = (unsigned short*)(ws + 3 * QKV_BYTES + (size_t)DMODEL * DMODEL * 2);

  cvt_qk<<<2048, 256, 0, stream>>>(queries, keys, Qb, Kb);
  vtrans<<<1024, 256, 0, stream>>>(values, Vt);
  cvt_w<<<512, 256, 0, stream>>>(fc_w, Wb);
  attn_fwd<<<NHTOT * (SEQ / 128), 256, 0, stream>>>(Qb, Kb, Vt, Ab);
  fc_gemm<<<(NBATCH * SEQ / 64) * (DMODEL / 64), 256, 0, stream>>>(Ab, Wb, fc_b, out);
}

// Round 6
// 186.294 us; speedup vs baseline: 1.1084x; 1.1084x over previous
//
#include <hip/hip_runtime.h>
#include <hip/hip_bf16.h>

#define NBATCH 2
#define SEQ    2048
#define DMODEL 1024
#define NHEAD  16
#define DHEAD  64
#define NHTOT  (NBATCH*NHEAD)   // 32

typedef __attribute__((ext_vector_type(8)))  short          short8;
typedef __attribute__((ext_vector_type(4)))  float          f32x4;
typedef __attribute__((ext_vector_type(16))) float          f32x16;
typedef __attribute__((ext_vector_type(4)))  unsigned short ushort4v;

__device__ __forceinline__ unsigned short f2bf(float x) {
  union { __hip_bfloat16 b; unsigned short u; } c;
  c.b = __float2bfloat16(x);
  return c.u;
}

__device__ __forceinline__ unsigned int cvt_pk_bf16(float lo, float hi) {
  unsigned int r;
  asm("v_cvt_pk_bf16_f32 %0, %1, %2" : "=v"(r) : "v"(lo), "v"(hi));
  return r;
}

// async global->LDS, 16B per lane; LDS dest = wave-uniform base + lane*16
__device__ __forceinline__ void gl_lds16(const unsigned short* g, unsigned short* l) {
  __builtin_amdgcn_global_load_lds(
      (const __attribute__((address_space(1))) void*)g,
      (__attribute__((address_space(3))) void*)l, 16, 0, 0);
}

// ---------------------------------------------------------------------------
// Kernel 1: Q,K fp32 -> bf16, per-head layout [NH][L][DK]; Q pre-scaled by
// log2(e)/sqrt(DK) so softmax = exp2(s - max). 8 elems/thread, 16B stores.
// ---------------------------------------------------------------------------
__global__ __launch_bounds__(256) void cvt_qk(const float* __restrict__ q,
                                              const float* __restrict__ k,
                                              unsigned short* __restrict__ qb,
                                              unsigned short* __restrict__ kb) {
  const float QSCALE = 0.125f * 1.44269504088896340736f;  // log2(e)/sqrt(64)
  int e = (blockIdx.x * 256 + threadIdx.x) * 8;
  int n = e >> 21;
  int r = e & ((1 << 21) - 1);
  int l = r >> 10;
  int c = r & 1023;
  int h = c >> 6;
  int d = c & 63;              // multiple of 8, stays within one head
  size_t dst = ((size_t)(n * NHEAD + h) * SEQ + l) * DHEAD + d;
  float4 q0 = *reinterpret_cast<const float4*>(q + e);
  float4 q1 = *reinterpret_cast<const float4*>(q + e + 4);
  float4 k0 = *reinterpret_cast<const float4*>(k + e);
  float4 k1 = *reinterpret_cast<const float4*>(k + e + 4);
  union { unsigned short u[8]; short8 s; } qo, ko;
  qo.u[0]=f2bf(q0.x*QSCALE); qo.u[1]=f2bf(q0.y*QSCALE);
  qo.u[2]=f2bf(q0.z*QSCALE); qo.u[3]=f2bf(q0.w*QSCALE);
  qo.u[4]=f2bf(q1.x*QSCALE); qo.u[5]=f2bf(q1.y*QSCALE);
  qo.u[6]=f2bf(q1.z*QSCALE); qo.u[7]=f2bf(q1.w*QSCALE);
  ko.u[0]=f2bf(k0.x); ko.u[1]=f2bf(k0.y); ko.u[2]=f2bf(k0.z); ko.u[3]=f2bf(k0.w);
  ko.u[4]=f2bf(k1.x); ko.u[5]=f2bf(k1.y); ko.u[6]=f2bf(k1.z); ko.u[7]=f2bf(k1.w);
  *reinterpret_cast<short8*>(qb + dst) = qo.s;
  *reinterpret_cast<short8*>(kb + dst) = ko.s;
}

// ---------------------------------------------------------------------------
// Kernel 2: V fp32 -> bf16 transposed per head: Vt[NH][DK][L]
// ---------------------------------------------------------------------------
__global__ __launch_bounds__(256) void vtrans(const float* __restrict__ v,
                                              unsigned short* __restrict__ vt) {
  __shared__ __align__(16) unsigned short t[64][76];
  int bid = blockIdx.x;
  int nh = bid >> 5;
  int lt = bid & 31;
  int n = nh >> 4, h = nh & 15;
  int lbase = lt * 64;
  #pragma unroll
  for (int p = 0; p < 4; ++p) {
    int idx = p * 256 + threadIdx.x;
    int e = idx * 4;
    int l = e >> 6, d = e & 63;  // d multiple of 4
    float4 x = *reinterpret_cast<const float4*>(
        v + ((size_t)n * SEQ + lbase + l) * DMODEL + h * DHEAD + d);
    ushort4v o;
    o.x = f2bf(x.x); o.y = f2bf(x.y); o.z = f2bf(x.z); o.w = f2bf(x.w);
    *reinterpret_cast<ushort4v*>(&t[l][d]) = o;
  }
  __syncthreads();
  #pragma unroll
  for (int p = 0; p < 4; ++p) {
    int idx = p * 256 + threadIdx.x;
    int d = idx >> 4, lq = (idx & 15) * 4;
    ushort4v o;
    o.x = t[lq + 0][d]; o.y = t[lq + 1][d];
    o.z = t[lq + 2][d]; o.w = t[lq + 3][d];
    *reinterpret_cast<ushort4v*>(
        vt + ((size_t)nh * DHEAD + d) * SEQ + lbase + lq) = o;
  }
}

// ---------------------------------------------------------------------------
// Kernel 3: fc weight fp32 -> bf16, 8 elems/thread
// ---------------------------------------------------------------------------
__global__ __launch_bounds__(256) void cvt_w(const float* __restrict__ w,
                                             unsigned short* __restrict__ wb) {
  int e = (blockIdx.x * 256 + threadIdx.x) * 8;
  float4 w0 = *reinterpret_cast<const float4*>(w + e);
  float4 w1 = *reinterpret_cast<const float4*>(w + e + 4);
  union { unsigned short u[8]; short8 s; } wo;
  wo.u[0]=f2bf(w0.x); wo.u[1]=f2bf(w0.y); wo.u[2]=f2bf(w0.z); wo.u[3]=f2bf(w0.w);
  wo.u[4]=f2bf(w1.x); wo.u[5]=f2bf(w1.y); wo.u[6]=f2bf(w1.z); wo.u[7]=f2bf(w1.w);
  *reinterpret_cast<short8*>(wb + e) = wo.s;
}

// ---------------------------------------------------------------------------
// Kernel 4: flash attention. 8 waves x QBLK=32 = 256 q/block, grid 256.
// mfma_32x32x16, swapped both ways (S[key][q], O[d][q]) -> lane-local softmax.
// gl_lds staging into a 3-BUFFER RING with counted vmcnt (T4): per iter
//   s_waitcnt vmcnt(2); s_barrier; stage(it+2); compute(it)
// -> tile loads get ~2 iterations to land, never drained to 0 in-loop.
// T12 cvt_pk+permlane P-pack, T13 defer-max, T5 setprio, tree reductions.
// ---------------------------------------------------------------------------
__global__ __launch_bounds__(512, 2) void attn_fwd(const unsigned short* __restrict__ Qb,
                                                   const unsigned short* __restrict__ Kb,
                                                   const unsigned short* __restrict__ Vt,
                                                   unsigned short* __restrict__ Ab) {
  // 3 bufs x (K 8KB + V 8KB) = 48KB; epilogue obuf (40KB) reuses it.
  __shared__ __align__(16) unsigned short smem[3 * 8192];

  const int bid = blockIdx.x;
  // XCD swizzle (T1): XCD = bid&7 owns 4 heads -> K/V L2-resident (2MB/XCD)
  const int nh = (bid & 7) * 4 + (bid >> 6);
  const int qt = (bid >> 3) & 7;
  const int tid  = threadIdx.x;
  const int wave = tid >> 6;
  const int lane = tid & 63;
  const int l31  = lane & 31;
  const int hi   = lane >> 5;

  const unsigned short* Kb_nh = Kb + (size_t)nh * SEQ * DHEAD;
  const unsigned short* Vt_nh = Vt + (size_t)nh * DHEAD * SEQ;

  const int qglob = qt * 256 + wave * 32 + l31;

  // Q B-frag: bq[ds] = Q[q=l31][d = ds*16 + hi*8 + j]
  short8 bq[4];
  {
    const unsigned short* Qrow = Qb + ((size_t)nh * SEQ + qglob) * DHEAD + hi * 8;
    #pragma unroll
    for (int ds = 0; ds < 4; ++ds)
      bq[ds] = *reinterpret_cast<const short8*>(Qrow + ds * 16);
  }

  float m_run = -1e30f, l_run = 0.f;
  f32x16 acc[2];
  #pragma unroll
  for (int dt = 0; dt < 2; ++dt)
    #pragma unroll
    for (int r = 0; r < 16; ++r) acc[dt][r] = 0.f;

  // stage tile t into ring buffer t%3; 1 K-chunk + 1 V-chunk (16B) per thread
  auto stage = [&](int t) {
    unsigned short* base = smem + (t % 3) * 8192;
    int kk  = t * 64;
    int row = tid >> 3, cs = tid & 7;
    int cg  = cs ^ (row & 7);          // inverse-swizzled global chunk
    int cb  = tid & 448;               // wave-uniform LDS chunk base
    gl_lds16(Kb_nh + (size_t)(kk + row) * DHEAD + cg * 8, base + cb * 8);
    gl_lds16(Vt_nh + (size_t)row * SEQ + kk + cg * 8,     base + 4096 + cb * 8);
  };

  const int NT = SEQ / 64;
  stage(0);
  stage(1);

  for (int it = 0; it < NT; ++it) {
    // counted vmcnt: tile-it loads (issued >=1 iter ago) complete; keep
    // tile-(it+1)'s 2 loads in flight. Drain fully only on the last iter.
    if (it + 1 < NT) asm volatile("s_waitcnt vmcnt(2)" ::: "memory");
    else             asm volatile("s_waitcnt vmcnt(0)" ::: "memory");
    __builtin_amdgcn_s_barrier();      // raw barrier: no compiler vmcnt(0) drain
    if (it + 2 < NT) stage(it + 2);    // buffer idle since iter it-1's barrier

    const unsigned short* kb = smem + (it % 3) * 8192;
    const unsigned short* vb = kb + 4096;

    // ---- QK^T: s[kt] covers keys kt*32 + (r&3)+8*(r>>2)+4*hi, q = l31 ----
    f32x16 s[2];
    __builtin_amdgcn_s_setprio(1);
    #pragma unroll
    for (int kt = 0; kt < 2; ++kt) {
      #pragma unroll
      for (int r = 0; r < 16; ++r) s[kt][r] = 0.f;
      const int row = kt * 32 + l31;
      const int sw  = row & 7;
      const unsigned short* kr = kb + row * 64;
      #pragma unroll
      for (int ds = 0; ds < 4; ++ds) {
        short8 ak = *reinterpret_cast<const short8*>(kr + (((ds * 2 + hi) ^ sw) * 8));
        s[kt] = __builtin_amdgcn_mfma_f32_32x32x16_bf16(ak, bq[ds], s[kt], 0, 0, 0);
      }
    }
    __builtin_amdgcn_s_setprio(0);

    // ---- online softmax, lane-local (q = l31); tree reductions ----
    float tr[16];
    #pragma unroll
    for (int i = 0; i < 16; ++i) tr[i] = fmaxf(s[0][i], s[1][i]);
    #pragma unroll
    for (int st = 8; st >= 1; st >>= 1)
      #pragma unroll
      for (int i = 0; i < st; ++i) tr[i] = fmaxf(tr[i], tr[i + st]);
    float pmax = fmaxf(tr[0], __shfl_xor(tr[0], 32));

    if (!__all(pmax - m_run <= 8.0f)) {          // T13 defer-max
      float mnew = fmaxf(m_run, pmax);
      float corr = exp2f(m_run - mnew);
      l_run *= corr;
      #pragma unroll
      for (int dt = 0; dt < 2; ++dt)
        #pragma unroll
        for (int r = 0; r < 16; ++r) acc[dt][r] *= corr;
      m_run = mnew;
    }

    #pragma unroll
    for (int kt = 0; kt < 2; ++kt)
      #pragma unroll
      for (int r = 0; r < 16; ++r) s[kt][r] = exp2f(s[kt][r] - m_run);
    #pragma unroll
    for (int i = 0; i < 16; ++i) tr[i] = s[0][i] + s[1][i];
    #pragma unroll
    for (int st = 8; st >= 1; st >>= 1)
      #pragma unroll
      for (int i = 0; i < st; ++i) tr[i] += tr[i + st];
    l_run += tr[0] + __shfl_xor(tr[0], 32);

    // ---- P -> bf16 in-register (T12): 16 cvt_pk + 8 permlane32_swap ----
    unsigned int pk[2][8];
    #pragma unroll
    for (int kt = 0; kt < 2; ++kt)
      #pragma unroll
      for (int i = 0; i < 8; ++i)
        pk[kt][i] = cvt_pk_bf16(s[kt][2 * i], s[kt][2 * i + 1]);

    unsigned int pa[4][4];
    #pragma unroll
    for (int ks = 0; ks < 4; ++ks) {
      const int t = ks >> 1, b = (ks & 1) * 4;
      pa[ks][0] = pk[t][b + 0]; pa[ks][2] = pk[t][b + 2];
      asm("v_permlane32_swap_b32 %0, %1" : "+v"(pa[ks][0]), "+v"(pa[ks][2]));
      pa[ks][1] = pk[t][b + 1]; pa[ks][3] = pk[t][b + 3];
      asm("v_permlane32_swap_b32 %0, %1" : "+v"(pa[ks][1]), "+v"(pa[ks][3]));
    }

    // ---- PV: acc[dt] += mfma(A=Vt rows d, B=P) -> O[d][q] ----
    __builtin_amdgcn_s_setprio(1);
    #pragma unroll
    for (int dt = 0; dt < 2; ++dt) {
      const int row = dt * 32 + l31;
      const int sw  = row & 7;
      const unsigned short* vr = vb + row * 64;
      #pragma unroll
      for (int ks = 0; ks < 4; ++ks) {
        short8 av = *reinterpret_cast<const short8*>(vr + (((ks * 2 + hi) ^ sw) * 8));
        union { unsigned int u[4]; short8 s8; } pu;
        pu.u[0] = pa[ks][0]; pu.u[1] = pa[ks][1];
        pu.u[2] = pa[ks][2]; pu.u[3] = pa[ks][3];
        acc[dt] = __builtin_amdgcn_mfma_f32_32x32x16_bf16(av, pu.s8, acc[dt], 0, 0, 0);
      }
    }
    __builtin_amdgcn_s_setprio(0);
  }

  __syncthreads();   // all waves done with ring buffers before obuf reuse

  // ---- epilogue: O[d][q]/l -> transpose via LDS -> coalesced bf16 rows ----
  unsigned short (*obuf)[32][80] = (unsigned short(*)[32][80])(&smem[0]);  // 40KB
  const float inv = 1.0f / l_run;     // lane-local (q = l31)
  const int n = nh >> 4, h = nh & 15;
  #pragma unroll
  for (int dt = 0; dt < 2; ++dt)
    #pragma unroll
    for (int q4 = 0; q4 < 4; ++q4) {
      ushort4v pv;
      pv.x = f2bf(acc[dt][q4 * 4 + 0] * inv);
      pv.y = f2bf(acc[dt][q4 * 4 + 1] * inv);
      pv.z = f2bf(acc[dt][q4 * 4 + 2] * inv);
      pv.w = f2bf(acc[dt][q4 * 4 + 3] * inv);
      *reinterpret_cast<ushort4v*>(&obuf[wave][l31][dt * 32 + q4 * 8 + hi * 4]) = pv;
    }
  __syncthreads();
  #pragma unroll
  for (int rep = 0; rep < 4; ++rep) {
    int idx = rep * 512 + tid;          // 256 rows x 8 chunks
    int qi = idx >> 3, ch = idx & 7;
    int w = qi >> 5, qr = qi & 31;
    ushort4v v0 = *reinterpret_cast<const ushort4v*>(&obuf[w][qr][ch * 8]);
    ushort4v v1 = *reinterpret_cast<const ushort4v*>(&obuf[w][qr][ch * 8 + 4]);
    union { ushort4v h[2]; short8 s; } vv;
    vv.h[0] = v0; vv.h[1] = v1;
    size_t orow = (size_t)n * SEQ + qt * 256 + qi;
    *reinterpret_cast<short8*>(Ab + orow * DMODEL + h * 64 + ch * 8) = vv.s;
  }
}

// ---------------------------------------------------------------------------
// Kernel 5: out = Ab(bf16) @ Wb^T + bias. 64x64 tile, BK=64, grid 1024,
// gl_lds staging into a 3-buffer ring with counted vmcnt (T4): per iter
// vmcnt(4); s_barrier; stage(it+2); compute(it). 3 blocks/CU (48KB LDS).
// ---------------------------------------------------------------------------
__global__ __launch_bounds__(256, 3) void fc_gemm(const unsigned short* __restrict__ Ab,
                                                  const unsigned short* __restrict__ Wb,
                                                  const float* __restrict__ bias,
                                                  float* __restrict__ out) {
  __shared__ __align__(16) unsigned short At[3][64 * 64];
  __shared__ __align__(16) unsigned short Bt[3][64 * 64];
  const int bid = blockIdx.x;
  const int bn = (bid & 7) * 2 + ((bid >> 3) & 1);  // XCD owns a Wb panel
  const int bm = bid >> 4;
  const int tid = threadIdx.x;
  const int wave = tid >> 6, lane = tid & 63;
  const int wr = wave >> 1, wc = wave & 1;
  const int l15 = lane & 15, l4 = lane >> 4;

  f32x4 acc[2][2];
  #pragma unroll
  for (int i = 0; i < 2; ++i)
    #pragma unroll
    for (int j = 0; j < 2; ++j) acc[i][j] = (f32x4){0.f, 0.f, 0.f, 0.f};

  auto stage = [&](int t) {
    int buf = t % 3, k0 = t * 64;
    #pragma unroll
    for (int j = 0; j < 2; ++j) {
      int c = j * 256 + tid;          // 512 chunks per 8KB tile
      int row = c >> 3, cs = c & 7;
      int cg = cs ^ (row & 7);        // inverse-swizzled global chunk
      int cb = j * 256 + (tid & 192); // wave-uniform LDS chunk base
      gl_lds16(Ab + (size_t)(bm * 64 + row) * DMODEL + k0 + cg * 8, &At[buf][cb * 8]);
      gl_lds16(Wb + (size_t)(bn * 64 + row) * DMODEL + k0 + cg * 8, &Bt[buf][cb * 8]);
    }
  };

  const int NT = DMODEL / 64;
  stage(0);
  stage(1);

  for (int it = 0; it < NT; ++it) {
    if (it + 1 < NT) asm volatile("s_waitcnt vmcnt(4)" ::: "memory");
    else             asm volatile("s_waitcnt vmcnt(0)" ::: "memory");
    __builtin_amdgcn_s_barrier();
    if (it + 2 < NT) stage(it + 2);
    int cur = it % 3;

    __builtin_amdgcn_s_setprio(1);
    #pragma unroll
    for (int s = 0; s < 2; ++s) {
      short8 af[2], bf2[2];
      #pragma unroll
      for (int mt = 0; mt < 2; ++mt) {
        int row = wr * 32 + mt * 16 + l15;
        af[mt] = *reinterpret_cast<const short8*>(
            &At[cur][row * 64 + (((s * 4 + l4) ^ (row & 7)) * 8)]);
      }
      #pragma unroll
      for (int nt = 0; nt < 2; ++nt) {
        int row = wc * 32 + nt * 16 + l15;
        bf2[nt] = *reinterpret_cast<const short8*>(
            &Bt[cur][row * 64 + (((s * 4 + l4) ^ (row & 7)) * 8)]);
      }
      #pragma unroll
      for (int mt = 0; mt < 2; ++mt)
        #pragma unroll
        for (int nt = 0; nt < 2; ++nt)
          acc[mt][nt] = __builtin_amdgcn_mfma_f32_16x16x32_bf16(af[mt], bf2[nt], acc[mt][nt], 0, 0, 0);
    }
    __builtin_amdgcn_s_setprio(0);
  }

  #pragma unroll
  for (int mt = 0; mt < 2; ++mt)
    #pragma unroll
    for (int nt = 0; nt < 2; ++nt) {
      int col = bn * 64 + wc * 32 + nt * 16 + l15;
      float bv = bias[col];
      #pragma unroll
      for (int r = 0; r < 4; ++r) {
        int row = bm * 64 + wr * 32 + mt * 16 + l4 * 4 + r;
        out[(size_t)row * DMODEL + col] = acc[mt][nt][r] + bv;
      }
    }
}

// ---------------------------------------------------------------------------
extern "C" void kernel_launch(void* const* d_in, const int* in_sizes, int n_in,
                              void* d_out, int out_size, void* d_ws, size_t ws_size,
                              hipStream_t stream) {
  const float* values  = (const float*)d_in[0];
  const float* keys    = (const float*)d_in[1];
  const float* queries = (const float*)d_in[2];
  const float* fc_w    = (const float*)d_in[3];
  const float* fc_b    = (const float*)d_in[4];
  float* out = (float*)d_out;

  char* ws = (char*)d_ws;
  const size_t QKV_BYTES = (size_t)NHTOT * SEQ * DHEAD * 2;  // 8 MB each
  unsigned short* Qb = (unsigned short*)(ws);
  unsigned short* Kb = (unsigned short*)(ws + QKV_BYTES);
  unsigned short* Vt = (unsigned short*)(ws + 2 * QKV_BYTES);
  unsigned short* Wb = (unsigned short*)(ws + 3 * QKV_BYTES);
  unsigned short* Ab = (unsigned short*)(ws + 3 * QKV_BYTES + (size_t)DMODEL * DMODEL * 2);

  cvt_qk<<<2048, 256, 0, stream>>>(queries, keys, Qb, Kb);
  vtrans<<<1024, 256, 0, stream>>>(values, Vt);
  cvt_w<<<512, 256, 0, stream>>>(fc_w, Wb);
  attn_fwd<<<NHTOT * (SEQ / 256), 512, 0, stream>>>(Qb, Kb, Vt, Ab);
  fc_gemm<<<(NBATCH * SEQ / 64) * (DMODEL / 64), 256, 0, stream>>>(Ab, Wb, fc_b, out);
}